// Round 2
// 1647.148 us; speedup vs baseline: 1.3914x; 1.3914x over previous
//
#include <hip/hip_runtime.h>
#include <hip/hip_fp16.h>
#include <stdint.h>

// y = (x @ W^T) * alpha + bias
// x: [M=8192, K=4096] fp32   W: [N=16384, K=4096] int8 (delivered widened to int32)
// bias: [N] fp16   out: [M,N] fp32
//
// R2: same 256x256 8-wave phase-interleaved template as R1, but the 128 KiB
// LDS is now STATIC __shared__ (gfx950 allows 160 KiB/WG) instead of dynamic
// shared + hipFuncSetAttribute — the attr call inside kernel_launch was the
// prime suspect for the R1 container failure (non-stream host call under
// graph capture; dynamic LDS >64 KiB is invalid without it).
//   T1 XCD-chunked block swizzle (grid=2048, %8==0 -> simple bijective form)
//   T2 st_16x32 LDS XOR swizzle, both-sides (inverse-swizzled global source +
//      swizzled ds_read; LDS write stays linear for global_load_lds)
//   T3/T4 per-phase interleave with counted vmcnt(8) (never 0 in main loop)
//   T5 s_setprio(1) around each 16-MFMA cluster
// Conversion prepass (fp32->bf16, int32->bf16) unchanged from the passing R0.

typedef __attribute__((ext_vector_type(8))) short short8;   // 8 bf16 = 4 VGPRs
typedef __attribute__((ext_vector_type(4))) float floatx4;  // MFMA acc

__device__ __forceinline__ void gld_lds16(const unsigned short* g,
                                          unsigned short* lds) {
  // async global->LDS, 16B/lane; LDS dest is wave-uniform base + lane*16
  __builtin_amdgcn_global_load_lds(
      (const __attribute__((address_space(1))) void*)g,
      (__attribute__((address_space(3))) void*)lds, 16, 0, 0);
}

__device__ __forceinline__ unsigned short f2bf_rne(float f) {
  union { float f; unsigned int u; } v; v.f = f;
  unsigned int u = v.u;
  u += 0x7FFFu + ((u >> 16) & 1u);  // round-to-nearest-even
  return (unsigned short)(u >> 16);
}

// ---- convert x fp32 -> bf16, 8 elems/thread (memory-bound) ----
__global__ __launch_bounds__(256) void cvt_x(const float* __restrict__ x,
                                             unsigned short* __restrict__ o) {
  long t = (long)blockIdx.x * 256 + threadIdx.x;
  long base = t * 8;
  const float4* xv = (const float4*)(x + base);
  float4 a = xv[0], b = xv[1];
  union { unsigned short s[8]; uint4 v; } r;
  r.s[0] = f2bf_rne(a.x); r.s[1] = f2bf_rne(a.y);
  r.s[2] = f2bf_rne(a.z); r.s[3] = f2bf_rne(a.w);
  r.s[4] = f2bf_rne(b.x); r.s[5] = f2bf_rne(b.y);
  r.s[6] = f2bf_rne(b.z); r.s[7] = f2bf_rne(b.w);
  *((uint4*)(o + base)) = r.v;
}

// ---- convert W int32 (one int8 value per int32!) -> bf16, 8 elems/thread ----
__global__ __launch_bounds__(256) void cvt_w(const int* __restrict__ w,
                                             unsigned short* __restrict__ o) {
  long t = (long)blockIdx.x * 256 + threadIdx.x;
  long base = t * 8;
  const int4 a = ((const int4*)(w + base))[0];
  const int4 b = ((const int4*)(w + base))[1];
  union { unsigned short s[8]; uint4 v; } r;
  r.s[0] = f2bf_rne((float)a.x);  // |v|<=127: exact in bf16
  r.s[1] = f2bf_rne((float)a.y);
  r.s[2] = f2bf_rne((float)a.z);
  r.s[3] = f2bf_rne((float)a.w);
  r.s[4] = f2bf_rne((float)b.x);
  r.s[5] = f2bf_rne((float)b.y);
  r.s[6] = f2bf_rne((float)b.z);
  r.s[7] = f2bf_rne((float)b.w);
  *((uint4*)(o + base)) = r.v;
}

#define KD 4096
#define KT_N 64  // KD / 64 K-tiles

// 256x256 tile, BK=64 as two 32-k units per operand; 8 waves (2M x 4N),
// per-wave output 128x64 = acc[8][4] (16x16x32 MFMA).
// LDS: 2buf x {A,B} x {khalf} x (256 rows x 32 k bf16 = 16 KiB) = 128 KiB,
// STATIC shared (gfx950 WG limit is 160 KiB).
// Unit physical layout: subtiled [rgrp=16][lrow=16][k=32] ushorts with
// st_16x32 swizzle k_phys = k ^ ((lrow&8)?16:0)  (bank-conflict floor on
// ds_read_b128 fragment reads — 8 lanes / bank-quad).
__global__ __launch_bounds__(512, 2) void gemm256(
    const unsigned short* __restrict__ A,   // [M][K] bf16
    const unsigned short* __restrict__ Bt,  // [N][K] bf16
    const __half* __restrict__ bias,        // [N] fp16
    const float* __restrict__ alpha_p,
    float* __restrict__ C, int M, int N) {
  __shared__ unsigned short smem[8 * 8192];  // 8 units x 16 KiB = 128 KiB

  const int tid = threadIdx.x;
  const int wave = tid >> 6, lane = tid & 63;

  // T1: XCD-chunked swizzle (gridDim.x == 2048, divisible by 8) then a
  // 4bm x 8bn supertile decode so each XCD's ~32 concurrent blocks share a
  // 384 KiB per-K-step working set in its private L2.
  const int orig = (int)blockIdx.x;
  const int wgid = (orig & 7) * ((int)gridDim.x >> 3) + (orig >> 3);
  const int l = wgid & 31;
  const int bm = (wgid >> 8) * 4 + (l & 3);           // 32 M-tiles
  const int bn = (((wgid >> 5) & 7) << 3) + (l >> 2); // 64 N-tiles

  const int wr = wave >> 2;  // 0..1 : M half
  const int wc = wave & 3;   // 0..3 : N quarter

  // --- staging: 1024 chunks of 16 B per unit; thread covers chunks tid and
  // tid+512. LDS dest linear (global_load_lds requirement); global source is
  // inverse-swizzled (both-sides rule, m201/m231).
  int off0, off1;
  {
    int idx = tid;
    int lrow = (idx >> 2) & 15;
    int k = ((idx & 3) << 3) ^ ((lrow & 8) ? 16 : 0);
    off0 = ((idx >> 6) * 16 + lrow) * KD + k;
    idx = tid + 512;
    lrow = (idx >> 2) & 15;
    k = ((idx & 3) << 3) ^ ((lrow & 8) ? 16 : 0);
    off1 = ((idx >> 6) * 16 + lrow) * KD + k;
  }
  const unsigned short* Apan = A + (size_t)bm * (256 * (size_t)KD);
  const unsigned short* Bpan = Bt + (size_t)bn * (256 * (size_t)KD);
  const int ldsW0 = wave * 512;         // chunk idx = tid     -> ushort ofs
  const int ldsW1 = 4096 + wave * 512;  // chunk idx = tid+512

  // --- fragment ds_read offsets: logical (row = base + (lane&15),
  // k = (lane>>4)*8), swizzled physical address.
  const int fr = lane & 15;
  const int fk = (lane >> 4) << 3;
  const int lane_rd = fr * 32 + (fk ^ ((fr & 8) ? 16 : 0));
  const int aBase = wr * 8 * 512 + lane_rd;  // + i*512, i=0..7
  const int bBase = wc * 4 * 512 + lane_rd;  // + j*512, j=0..3

  floatx4 acc[8][4];
#pragma unroll
  for (int i = 0; i < 8; i++)
#pragma unroll
    for (int j = 0; j < 4; j++) acc[i][j] = (floatx4){0.f, 0.f, 0.f, 0.f};

#define UNIT(buf, op, kh) \
  (smem + ((((((buf) << 1) | (op)) << 1) | (kh)) << 13))
#define STAGE(buf, op, kh, kt, pan)                               \
  do {                                                            \
    const unsigned short* _s = (pan) + ((kt) << 6) + ((kh) << 5); \
    unsigned short* _u = UNIT(buf, op, kh);                       \
    gld_lds16(_s + off0, _u + ldsW0);                             \
    gld_lds16(_s + off1, _u + ldsW1);                             \
  } while (0)
#define BARRIER() asm volatile("s_barrier" ::: "memory")
#define WAIT_LGKM0() asm volatile("s_waitcnt lgkmcnt(0)" ::: "memory")
#define WAIT_VM8() asm volatile("s_waitcnt vmcnt(8)" ::: "memory")

  // prologue: tile0 all 4 units + tile1 k0 units (12 loads); drain oldest 4
  // (tile0 k0) -> 8 in flight entering the loop.
  STAGE(0, 0, 0, 0, Apan); STAGE(0, 1, 0, 0, Bpan);
  STAGE(0, 0, 1, 0, Apan); STAGE(0, 1, 1, 0, Bpan);
  STAGE(1, 0, 0, 1, Apan); STAGE(1, 1, 0, 1, Bpan);
  WAIT_VM8();
  BARRIER();

  short8 af[8], bf[2];
#pragma unroll 2
  for (int t = 0; t < KT_N; ++t) {
    const int b = t & 1;
    const int kt1 = (t + 1) & (KT_N - 1);  // wrap keeps vmcnt counts uniform;
    const int kt2 = (t + 2) & (KT_N - 1);  // 2 wasted tail units, never read
    const unsigned short* a0 = UNIT(b, 0, 0);
    const unsigned short* b0 = UNIT(b, 1, 0);
    const unsigned short* a1 = UNIT(b, 0, 1);
    const unsigned short* b1 = UNIT(b, 1, 1);

    // ---- phase 1: ks=0, j={0,1}; prefetch A-k1 of tile t+1 (other buf)
#pragma unroll
    for (int i = 0; i < 8; i++) af[i] = *(const short8*)(a0 + aBase + i * 512);
    bf[0] = *(const short8*)(b0 + bBase);
    bf[1] = *(const short8*)(b0 + bBase + 512);
    STAGE(b ^ 1, 0, 1, kt1, Apan);
    BARRIER();
    WAIT_LGKM0();
    __builtin_amdgcn_s_setprio(1);
#pragma unroll
    for (int i = 0; i < 8; i++) {
      acc[i][0] = __builtin_amdgcn_mfma_f32_16x16x32_bf16(af[i], bf[0], acc[i][0], 0, 0, 0);
      acc[i][1] = __builtin_amdgcn_mfma_f32_16x16x32_bf16(af[i], bf[1], acc[i][1], 0, 0, 0);
    }
    __builtin_amdgcn_s_setprio(0);
    BARRIER();

    // ---- phase 2: ks=0, j={2,3}; prefetch B-k1 of tile t+1
    bf[0] = *(const short8*)(b0 + bBase + 2 * 512);
    bf[1] = *(const short8*)(b0 + bBase + 3 * 512);
    STAGE(b ^ 1, 1, 1, kt1, Bpan);
    BARRIER();
    WAIT_LGKM0();
    __builtin_amdgcn_s_setprio(1);
#pragma unroll
    for (int i = 0; i < 8; i++) {
      acc[i][2] = __builtin_amdgcn_mfma_f32_16x16x32_bf16(af[i], bf[0], acc[i][2], 0, 0, 0);
      acc[i][3] = __builtin_amdgcn_mfma_f32_16x16x32_bf16(af[i], bf[1], acc[i][3], 0, 0, 0);
    }
    __builtin_amdgcn_s_setprio(0);
    WAIT_VM8();  // retires this tile's k1 units (read by phases 3/4);
    BARRIER();   // wait-before-barrier publishes all waves' landings

    // ---- phase 3: ks=1, j={0,1}; prefetch A-k0 of tile t+2 (same buf —
    // that region's readers all retired at phase-2's end barrier)
#pragma unroll
    for (int i = 0; i < 8; i++) af[i] = *(const short8*)(a1 + aBase + i * 512);
    bf[0] = *(const short8*)(b1 + bBase);
    bf[1] = *(const short8*)(b1 + bBase + 512);
    STAGE(b, 0, 0, kt2, Apan);
    BARRIER();
    WAIT_LGKM0();
    __builtin_amdgcn_s_setprio(1);
#pragma unroll
    for (int i = 0; i < 8; i++) {
      acc[i][0] = __builtin_amdgcn_mfma_f32_16x16x32_bf16(af[i], bf[0], acc[i][0], 0, 0, 0);
      acc[i][1] = __builtin_amdgcn_mfma_f32_16x16x32_bf16(af[i], bf[1], acc[i][1], 0, 0, 0);
    }
    __builtin_amdgcn_s_setprio(0);
    BARRIER();

    // ---- phase 4: ks=1, j={2,3}; prefetch B-k0 of tile t+2
    bf[0] = *(const short8*)(b1 + bBase + 2 * 512);
    bf[1] = *(const short8*)(b1 + bBase + 3 * 512);
    STAGE(b, 1, 0, kt2, Bpan);
    BARRIER();
    WAIT_LGKM0();
    __builtin_amdgcn_s_setprio(1);
#pragma unroll
    for (int i = 0; i < 8; i++) {
      acc[i][2] = __builtin_amdgcn_mfma_f32_16x16x32_bf16(af[i], bf[0], acc[i][2], 0, 0, 0);
      acc[i][3] = __builtin_amdgcn_mfma_f32_16x16x32_bf16(af[i], bf[1], acc[i][3], 0, 0, 0);
    }
    __builtin_amdgcn_s_setprio(0);
    WAIT_VM8();  // retires tile t+1's k0 units (read by next iter's ph 1/2)
    BARRIER();
  }
  asm volatile("s_waitcnt vmcnt(0)" ::: "memory");  // drain before endpgm

  // epilogue: C/D layout col=lane&15, row=(lane>>4)*4+r  [m89/m91-verified]
  const float alpha = *alpha_p;
  const int erow = (lane >> 4) * 4;
  const int ecol = lane & 15;
  const long row0 = (long)bm * 256 + wr * 128;
  const int col0 = bn * 256 + wc * 64;
#pragma unroll
  for (int j = 0; j < 4; j++) {
    const int col = col0 + j * 16 + ecol;
    const float bv = __half2float(bias[col]);
#pragma unroll
    for (int i = 0; i < 8; i++) {
      const long row = row0 + i * 16 + erow;
#pragma unroll
      for (int r = 0; r < 4; r++)
        C[(row + r) * (long)N + col] = acc[i][j][r] * alpha + bv;
    }
  }
#undef UNIT
#undef STAGE
#undef BARRIER
#undef WAIT_LGKM0
#undef WAIT_VM8
}

extern "C" void kernel_launch(void* const* d_in, const int* in_sizes, int n_in,
                              void* d_out, int out_size, void* d_ws,
                              size_t ws_size, hipStream_t stream) {
  const float* x     = (const float*)d_in[0];  // [M,K] fp32
  const int* w       = (const int*)d_in[1];    // [N,K] int32 (widened int8)
  const __half* bias = (const __half*)d_in[2]; // [N] fp16
  const float* alpha = (const float*)d_in[3];  // scalar fp32
  float* out         = (float*)d_out;

  const int K = 4096;
  const int N = in_sizes[2];      // 16384
  const int M = in_sizes[0] / K;  // 8192

  // workspace: [ W bf16 : N*K*2 B = 128 MiB ][ X bf16 : M*K*2 B = 64 MiB ]
  unsigned short* Wbf = (unsigned short*)d_ws;
  unsigned short* Xbf = Wbf + (size_t)N * K;
  (void)ws_size; (void)n_in; (void)out_size;

  {  // W: N*K/8 threads, 8 int32 -> 8 bf16 each
    long nthreads = (long)N * K / 8;
    cvt_w<<<dim3((unsigned)(nthreads / 256)), dim3(256), 0, stream>>>(w, Wbf);
  }
  {  // X: M*K/8 threads
    long nthreads = (long)M * K / 8;
    cvt_x<<<dim3((unsigned)(nthreads / 256)), dim3(256), 0, stream>>>(x, Xbf);
  }

  gemm256<<<dim3((M / 256) * (N / 256)), dim3(512), 0, stream>>>(
      Xbf, Wbf, bias, alpha, out, M, N);
}

// Round 3
// 1635.637 us; speedup vs baseline: 1.4011x; 1.0070x over previous
//
#include <hip/hip_runtime.h>
#include <hip/hip_fp16.h>
#include <stdint.h>

// y = (x @ W^T) * alpha + bias
// x: [M=8192, K=4096] fp32   W: [N=16384, K=4096] int8 (delivered widened to int32)
// bias: [N] fp16   out: [M,N] fp32
//
// R3: R2 hit MfmaUtil 51% = 620cyc MFMA / (620 MFMA + 580 LDS-drain) per phase:
// the explicit s_waitcnt lgkmcnt(0) serialized the ds_read drain against the
// MFMA cluster. Fix: remove the drain, order reads consumption-first
// (bf0,bf1,af0..7) and let the compiler emit progressive lgkmcnt(N) per-use
// waits so the LDS pipe streams reads UNDER the MFMA cluster.
// Hazard audit: every frag is consumed (-> compiler lgkm wait) before the
// barrier preceding its unit's overwriting STAGE, so read-before-overwrite
// stays closed; cross-wave staging publish still vmcnt(8)-before-barrier.
//   T1 XCD-chunked block swizzle  T2 st_16x32 both-sides swizzle (0 conflicts)
//   T3/T4 counted vmcnt(8), never 0 in loop   T5 setprio around MFMA clusters
// cvt kernels: grid-stride with capped 4096-block grid (G11).

typedef __attribute__((ext_vector_type(8))) short short8;   // 8 bf16 = 4 VGPRs
typedef __attribute__((ext_vector_type(4))) float floatx4;  // MFMA acc

__device__ __forceinline__ void gld_lds16(const unsigned short* g,
                                          unsigned short* lds) {
  // async global->LDS, 16B/lane; LDS dest is wave-uniform base + lane*16
  __builtin_amdgcn_global_load_lds(
      (const __attribute__((address_space(1))) void*)g,
      (__attribute__((address_space(3))) void*)lds, 16, 0, 0);
}

__device__ __forceinline__ unsigned short f2bf_rne(float f) {
  union { float f; unsigned int u; } v; v.f = f;
  unsigned int u = v.u;
  u += 0x7FFFu + ((u >> 16) & 1u);  // round-to-nearest-even
  return (unsigned short)(u >> 16);
}

// ---- convert x fp32 -> bf16, 8 elems/iter/thread, grid-stride ----
__global__ __launch_bounds__(256) void cvt_x(const float* __restrict__ x,
                                             unsigned short* __restrict__ o,
                                             long n8) {
  const long stride = (long)gridDim.x * 256;
  for (long t = (long)blockIdx.x * 256 + threadIdx.x; t < n8; t += stride) {
    long base = t * 8;
    const float4* xv = (const float4*)(x + base);
    float4 a = xv[0], b = xv[1];
    union { unsigned short s[8]; uint4 v; } r;
    r.s[0] = f2bf_rne(a.x); r.s[1] = f2bf_rne(a.y);
    r.s[2] = f2bf_rne(a.z); r.s[3] = f2bf_rne(a.w);
    r.s[4] = f2bf_rne(b.x); r.s[5] = f2bf_rne(b.y);
    r.s[6] = f2bf_rne(b.z); r.s[7] = f2bf_rne(b.w);
    *((uint4*)(o + base)) = r.v;
  }
}

// ---- convert W int32 (one int8 value per int32!) -> bf16, grid-stride ----
__global__ __launch_bounds__(256) void cvt_w(const int* __restrict__ w,
                                             unsigned short* __restrict__ o,
                                             long n8) {
  const long stride = (long)gridDim.x * 256;
  for (long t = (long)blockIdx.x * 256 + threadIdx.x; t < n8; t += stride) {
    long base = t * 8;
    const int4 a = ((const int4*)(w + base))[0];
    const int4 b = ((const int4*)(w + base))[1];
    union { unsigned short s[8]; uint4 v; } r;
    r.s[0] = f2bf_rne((float)a.x);  // |v|<=127: exact in bf16
    r.s[1] = f2bf_rne((float)a.y);
    r.s[2] = f2bf_rne((float)a.z);
    r.s[3] = f2bf_rne((float)a.w);
    r.s[4] = f2bf_rne((float)b.x);
    r.s[5] = f2bf_rne((float)b.y);
    r.s[6] = f2bf_rne((float)b.z);
    r.s[7] = f2bf_rne((float)b.w);
    *((uint4*)(o + base)) = r.v;
  }
}

#define KD 4096
#define KT_N 64  // KD / 64 K-tiles

// 256x256 tile, BK=64 as two 32-k units per operand; 8 waves (2M x 4N),
// per-wave output 128x64 = acc[8][4] (16x16x32 MFMA).
// LDS: 2buf x {A,B} x {khalf} x (256 rows x 32 k bf16 = 16 KiB) = 128 KiB,
// static shared (gfx950 WG limit 160 KiB) -> 1 WG/CU, 2 waves/SIMD.
// Unit layout: subtiled [rgrp=16][lrow=16][k=32] ushorts, st_16x32 swizzle
// k_phys = k ^ ((lrow&8)?16:0) — measured 0 bank conflicts (R2).
__global__ __launch_bounds__(512, 2) void gemm256(
    const unsigned short* __restrict__ A,   // [M][K] bf16
    const unsigned short* __restrict__ Bt,  // [N][K] bf16
    const __half* __restrict__ bias,        // [N] fp16
    const float* __restrict__ alpha_p,
    float* __restrict__ C, int M, int N) {
  __shared__ unsigned short smem[8 * 8192];  // 8 units x 16 KiB = 128 KiB

  const int tid = threadIdx.x;
  const int wave = tid >> 6, lane = tid & 63;

  // T1: XCD-chunked swizzle (gridDim.x == 2048, divisible by 8) then a
  // 4bm x 8bn supertile decode for per-XCD L2 locality.
  const int orig = (int)blockIdx.x;
  const int wgid = (orig & 7) * ((int)gridDim.x >> 3) + (orig >> 3);
  const int l = wgid & 31;
  const int bm = (wgid >> 8) * 4 + (l & 3);           // 32 M-tiles
  const int bn = (((wgid >> 5) & 7) << 3) + (l >> 2); // 64 N-tiles

  const int wr = wave >> 2;  // 0..1 : M half
  const int wc = wave & 3;   // 0..3 : N quarter

  // staging: 1024 chunks of 16 B per unit; thread covers chunks tid, tid+512.
  // LDS dest linear (global_load_lds requirement); global source
  // inverse-swizzled (both-sides rule).
  int off0, off1;
  {
    int idx = tid;
    int lrow = (idx >> 2) & 15;
    int k = ((idx & 3) << 3) ^ ((lrow & 8) ? 16 : 0);
    off0 = ((idx >> 6) * 16 + lrow) * KD + k;
    idx = tid + 512;
    lrow = (idx >> 2) & 15;
    k = ((idx & 3) << 3) ^ ((lrow & 8) ? 16 : 0);
    off1 = ((idx >> 6) * 16 + lrow) * KD + k;
  }
  const unsigned short* Apan = A + (size_t)bm * (256 * (size_t)KD);
  const unsigned short* Bpan = Bt + (size_t)bn * (256 * (size_t)KD);
  const int ldsW0 = wave * 512;         // chunk idx = tid     -> ushort ofs
  const int ldsW1 = 4096 + wave * 512;  // chunk idx = tid+512

  // fragment ds_read offsets: logical (row = base + (lane&15),
  // k = (lane>>4)*8), swizzled physical address.
  const int fr = lane & 15;
  const int fk = (lane >> 4) << 3;
  const int lane_rd = fr * 32 + (fk ^ ((fr & 8) ? 16 : 0));
  const int aBase = wr * 8 * 512 + lane_rd;  // + i*512, i=0..7
  const int bBase = wc * 4 * 512 + lane_rd;  // + j*512, j=0..3

  floatx4 acc[8][4];
#pragma unroll
  for (int i = 0; i < 8; i++)
#pragma unroll
    for (int j = 0; j < 4; j++) acc[i][j] = (floatx4){0.f, 0.f, 0.f, 0.f};

#define UNIT(buf, op, kh) \
  (smem + ((((((buf) << 1) | (op)) << 1) | (kh)) << 13))
#define STAGE(buf, op, kh, kt, pan)                               \
  do {                                                            \
    const unsigned short* _s = (pan) + ((kt) << 6) + ((kh) << 5); \
    unsigned short* _u = UNIT(buf, op, kh);                       \
    gld_lds16(_s + off0, _u + ldsW0);                             \
    gld_lds16(_s + off1, _u + ldsW1);                             \
  } while (0)
#define BARRIER() asm volatile("s_barrier" ::: "memory")
#define WAIT_VM8() asm volatile("s_waitcnt vmcnt(8)" ::: "memory")

  // prologue: tile0 all 4 units + tile1 k0 units (12 loads); drain oldest 4
  // (tile0 k0) -> 8 in flight entering the loop.
  STAGE(0, 0, 0, 0, Apan); STAGE(0, 1, 0, 0, Bpan);
  STAGE(0, 0, 1, 0, Apan); STAGE(0, 1, 1, 0, Bpan);
  STAGE(1, 0, 0, 1, Apan); STAGE(1, 1, 0, 1, Bpan);
  WAIT_VM8();
  BARRIER();

  short8 af[8], bf[2];
#pragma unroll 2
  for (int t = 0; t < KT_N; ++t) {
    const int b = t & 1;
    const int kt1 = (t + 1) & (KT_N - 1);  // wrap keeps vmcnt counts uniform;
    const int kt2 = (t + 2) & (KT_N - 1);  // 2 wasted tail units, never read
    const unsigned short* a0 = UNIT(b, 0, 0);
    const unsigned short* b0 = UNIT(b, 1, 0);
    const unsigned short* a1 = UNIT(b, 0, 1);
    const unsigned short* b1 = UNIT(b, 1, 1);

    // ---- phase 1: ks=0, j={0,1}; prefetch A-k1 of tile t+1 (other buf).
    // Reads consumption-first: bf0,bf1,af0..7 -> compiler's progressive
    // lgkmcnt lets MFMA i=0 start after 3 loads while af1..7 stream in.
    bf[0] = *(const short8*)(b0 + bBase);
    bf[1] = *(const short8*)(b0 + bBase + 512);
#pragma unroll
    for (int i = 0; i < 8; i++) af[i] = *(const short8*)(a0 + aBase + i * 512);
    STAGE(b ^ 1, 0, 1, kt1, Apan);
    BARRIER();
    __builtin_amdgcn_s_setprio(1);
#pragma unroll
    for (int i = 0; i < 8; i++) {
      acc[i][0] = __builtin_amdgcn_mfma_f32_16x16x32_bf16(af[i], bf[0], acc[i][0], 0, 0, 0);
      acc[i][1] = __builtin_amdgcn_mfma_f32_16x16x32_bf16(af[i], bf[1], acc[i][1], 0, 0, 0);
    }
    __builtin_amdgcn_s_setprio(0);
    BARRIER();

    // ---- phase 2: ks=0, j={2,3}; prefetch B-k1 of tile t+1
    bf[0] = *(const short8*)(b0 + bBase + 2 * 512);
    bf[1] = *(const short8*)(b0 + bBase + 3 * 512);
    STAGE(b ^ 1, 1, 1, kt1, Bpan);
    BARRIER();
    __builtin_amdgcn_s_setprio(1);
#pragma unroll
    for (int i = 0; i < 8; i++) {
      acc[i][2] = __builtin_amdgcn_mfma_f32_16x16x32_bf16(af[i], bf[0], acc[i][2], 0, 0, 0);
      acc[i][3] = __builtin_amdgcn_mfma_f32_16x16x32_bf16(af[i], bf[1], acc[i][3], 0, 0, 0);
    }
    __builtin_amdgcn_s_setprio(0);
    WAIT_VM8();  // retires this tile's k1 units (read by phases 3/4);
    BARRIER();   // wait-before-barrier publishes all waves' landings

    // ---- phase 3: ks=1, j={0,1}; prefetch A-k0 of tile t+2 (same buf —
    // that region's readers all retired at phase-2's end barrier)
    bf[0] = *(const short8*)(b1 + bBase);
    bf[1] = *(const short8*)(b1 + bBase + 512);
#pragma unroll
    for (int i = 0; i < 8; i++) af[i] = *(const short8*)(a1 + aBase + i * 512);
    STAGE(b, 0, 0, kt2, Apan);
    BARRIER();
    __builtin_amdgcn_s_setprio(1);
#pragma unroll
    for (int i = 0; i < 8; i++) {
      acc[i][0] = __builtin_amdgcn_mfma_f32_16x16x32_bf16(af[i], bf[0], acc[i][0], 0, 0, 0);
      acc[i][1] = __builtin_amdgcn_mfma_f32_16x16x32_bf16(af[i], bf[1], acc[i][1], 0, 0, 0);
    }
    __builtin_amdgcn_s_setprio(0);
    BARRIER();

    // ---- phase 4: ks=1, j={2,3}; prefetch B-k0 of tile t+2
    bf[0] = *(const short8*)(b1 + bBase + 2 * 512);
    bf[1] = *(const short8*)(b1 + bBase + 3 * 512);
    STAGE(b, 1, 0, kt2, Bpan);
    BARRIER();
    __builtin_amdgcn_s_setprio(1);
#pragma unroll
    for (int i = 0; i < 8; i++) {
      acc[i][2] = __builtin_amdgcn_mfma_f32_16x16x32_bf16(af[i], bf[0], acc[i][2], 0, 0, 0);
      acc[i][3] = __builtin_amdgcn_mfma_f32_16x16x32_bf16(af[i], bf[1], acc[i][3], 0, 0, 0);
    }
    __builtin_amdgcn_s_setprio(0);
    WAIT_VM8();  // retires tile t+1's k0 units (read by next iter's ph 1/2)
    BARRIER();
  }
  asm volatile("s_waitcnt vmcnt(0)" ::: "memory");  // drain before endpgm

  // epilogue: C/D layout col=lane&15, row=(lane>>4)*4+r  [m89/m91-verified]
  const float alpha = *alpha_p;
  const int erow = (lane >> 4) * 4;
  const int ecol = lane & 15;
  const long row0 = (long)bm * 256 + wr * 128;
  const int col0 = bn * 256 + wc * 64;
#pragma unroll
  for (int j = 0; j < 4; j++) {
    const int col = col0 + j * 16 + ecol;
    const float bv = __half2float(bias[col]);
#pragma unroll
    for (int i = 0; i < 8; i++) {
      const long row = row0 + i * 16 + erow;
#pragma unroll
      for (int r = 0; r < 4; r++)
        C[(row + r) * (long)N + col] = acc[i][j][r] * alpha + bv;
    }
  }
#undef UNIT
#undef STAGE
#undef BARRIER
#undef WAIT_VM8
}

extern "C" void kernel_launch(void* const* d_in, const int* in_sizes, int n_in,
                              void* d_out, int out_size, void* d_ws,
                              size_t ws_size, hipStream_t stream) {
  const float* x     = (const float*)d_in[0];  // [M,K] fp32
  const int* w       = (const int*)d_in[1];    // [N,K] int32 (widened int8)
  const __half* bias = (const __half*)d_in[2]; // [N] fp16
  const float* alpha = (const float*)d_in[3];  // scalar fp32
  float* out         = (float*)d_out;

  const int K = 4096;
  const int N = in_sizes[2];      // 16384
  const int M = in_sizes[0] / K;  // 8192

  // workspace: [ W bf16 : N*K*2 B = 128 MiB ][ X bf16 : M*K*2 B = 64 MiB ]
  unsigned short* Wbf = (unsigned short*)d_ws;
  unsigned short* Xbf = Wbf + (size_t)N * K;
  (void)ws_size; (void)n_in; (void)out_size;

  cvt_w<<<dim3(4096), dim3(256), 0, stream>>>(w, Wbf, (long)N * K / 8);
  cvt_x<<<dim3(4096), dim3(256), 0, stream>>>(x, Xbf, (long)M * K / 8);

  gemm256<<<dim3((M / 256) * (N / 256)), dim3(512), 0, stream>>>(
      Xbf, Wbf, bias, alpha, out, M, N);
}